// Round 2
// baseline (2287.428 us; speedup 1.0000x reference)
//
#include <hip/hip_runtime.h>

#define SEQLEN 2048
#define NHEADS 64
#define PDIM 64
#define NSTATE 128
#define CSIZE 256
#define NCHUNK 8
#define DINNER 4096
#define CONVD 4352
#define PROJD 8512

using s8v = __attribute__((ext_vector_type(8))) short;
using f4v = __attribute__((ext_vector_type(4))) float;
using bf8v = __attribute__((ext_vector_type(8))) __bf16;

__device__ __forceinline__ short f2bf(float x) {
  union { float f; unsigned u; } t; t.f = x;
  unsigned r = t.u + 0x7FFFu + ((t.u >> 16) & 1u);
  return (short)(r >> 16);
}
__device__ __forceinline__ float bf2f(short s) {
  union { unsigned u; float f; } t;
  t.u = ((unsigned)(unsigned short)s) << 16;
  return t.f;
}

__device__ __forceinline__ f4v mfma_bf16(s8v a, s8v b, f4v c) {
  return __builtin_amdgcn_mfma_f32_16x16x32_bf16(
      __builtin_bit_cast(bf8v, a), __builtin_bit_cast(bf8v, b), c, 0, 0, 0);
}

// ---------------------------------------------------------------- casts
__global__ __launch_bounds__(256) void cast_bf16_kernel(
    const float* __restrict__ in, short* __restrict__ out, int n4) {
  int i = blockIdx.x * 256 + threadIdx.x;
  if (i < n4) {
    float4 v = ((const float4*)in)[i];
    short4 o;
    o.x = f2bf(v.x); o.y = f2bf(v.y); o.z = f2bf(v.z); o.w = f2bf(v.w);
    ((short4*)out)[i] = o;
  }
}

// ------------------------------------------- GEMM1 with split epilogue
// proj = hidden @ W_in^T ; cols [0,4096)->z bf16, [4096,8448)->xBC bf16,
// [8448,8512)->dt fp32.  M=4096, N=8512, K=2048. grid (67,32).
__global__ __launch_bounds__(256) void gemm1_kernel(
    const short* __restrict__ A, const short* __restrict__ B,
    short* __restrict__ z, short* __restrict__ xbc, float* __restrict__ dtb) {
  const int N = PROJD, K = 2048;
  const int tn0 = blockIdx.x * 128;
  const int tm0 = blockIdx.y * 128;
  __shared__ short As[128][48];
  __shared__ short Bs[128][48];
  const int tid = threadIdx.x;
  const int lane = tid & 63, wid = tid >> 6;
  const int wm = (wid >> 1) * 64, wn = (wid & 1) * 64;
  const int lr = lane & 15, q = lane >> 4;
  f4v acc[4][4];
  for (int i = 0; i < 4; i++)
    for (int j = 0; j < 4; j++)
      for (int r = 0; r < 4; r++) acc[i][j][r] = 0.f;

  for (int k0 = 0; k0 < K; k0 += 32) {
    __syncthreads();
    for (int rr = 0; rr < 2; rr++) {
      int idx = tid + rr * 256;
      int row = idx >> 2;
      int col8 = (idx & 3) * 8;
      *(s8v*)&As[row][col8] = *(const s8v*)&A[(size_t)(tm0 + row) * K + k0 + col8];
      int gn = tn0 + row;
      s8v v;
      if (gn < N) v = *(const s8v*)&B[(size_t)gn * K + k0 + col8];
      else { for (int t = 0; t < 8; t++) v[t] = 0; }
      *(s8v*)&Bs[row][col8] = v;
    }
    __syncthreads();
    s8v af[4], bf_[4];
    for (int i = 0; i < 4; i++) af[i]  = *(const s8v*)&As[wm + i * 16 + lr][q * 8];
    for (int j = 0; j < 4; j++) bf_[j] = *(const s8v*)&Bs[wn + j * 16 + lr][q * 8];
    for (int i = 0; i < 4; i++)
      for (int j = 0; j < 4; j++)
        acc[i][j] = mfma_bf16(af[i], bf_[j], acc[i][j]);
  }
  for (int i = 0; i < 4; i++)
    for (int j = 0; j < 4; j++) {
      int c0 = tn0 + wn + j * 16 + lr;
      for (int r = 0; r < 4; r++) {
        int row = tm0 + wm + i * 16 + q * 4 + r;
        float v = acc[i][j][r];
        if (c0 < DINNER) {
          z[(size_t)row * DINNER + c0] = f2bf(v);
        } else if (c0 < DINNER + CONVD) {
          xbc[(size_t)row * CONVD + (c0 - DINNER)] = f2bf(v);
        } else if (c0 < PROJD) {
          dtb[(size_t)row * NHEADS + (c0 - DINNER - CONVD)] = v;
        }
      }
    }
}

// ------------------------------------------------- generic NT GEMM (GEMM2)
__global__ __launch_bounds__(256) void gemm_nt_bf16(
    const short* __restrict__ A, const short* __restrict__ B,
    float* __restrict__ C, int M, int N, int K) {
  const int tn0 = blockIdx.x * 128;
  const int tm0 = blockIdx.y * 128;
  __shared__ short As[128][48];
  __shared__ short Bs[128][48];
  const int tid = threadIdx.x;
  const int lane = tid & 63, wid = tid >> 6;
  const int wm = (wid >> 1) * 64, wn = (wid & 1) * 64;
  const int lr = lane & 15, q = lane >> 4;
  f4v acc[4][4];
  for (int i = 0; i < 4; i++)
    for (int j = 0; j < 4; j++)
      for (int r = 0; r < 4; r++) acc[i][j][r] = 0.f;

  for (int k0 = 0; k0 < K; k0 += 32) {
    __syncthreads();
    for (int rr = 0; rr < 2; rr++) {
      int idx = tid + rr * 256;
      int row = idx >> 2;
      int col8 = (idx & 3) * 8;
      *(s8v*)&As[row][col8] = *(const s8v*)&A[(size_t)(tm0 + row) * K + k0 + col8];
      int gn = tn0 + row;
      s8v v;
      if (gn < N) v = *(const s8v*)&B[(size_t)gn * K + k0 + col8];
      else { for (int t = 0; t < 8; t++) v[t] = 0; }
      *(s8v*)&Bs[row][col8] = v;
    }
    __syncthreads();
    s8v af[4], bf_[4];
    for (int i = 0; i < 4; i++) af[i]  = *(const s8v*)&As[wm + i * 16 + lr][q * 8];
    for (int j = 0; j < 4; j++) bf_[j] = *(const s8v*)&Bs[wn + j * 16 + lr][q * 8];
    for (int i = 0; i < 4; i++)
      for (int j = 0; j < 4; j++)
        acc[i][j] = mfma_bf16(af[i], bf_[j], acc[i][j]);
  }
  for (int i = 0; i < 4; i++)
    for (int j = 0; j < 4; j++) {
      int r0 = tm0 + wm + i * 16 + q * 4;
      int c0 = tn0 + wn + j * 16 + lr;
      if (c0 < N)
        for (int r = 0; r < 4; r++)
          C[(size_t)(r0 + r) * N + c0] = acc[i][j][r];
    }
}

// ------------------------------------------------ depthwise conv + SiLU
__global__ __launch_bounds__(256) void conv_silu_kernel(
    const short* __restrict__ xbc, const float* __restrict__ conv_w,
    const float* __restrict__ conv_b, short* __restrict__ xBCc) {
  int cc = blockIdx.x * 256 + threadIdx.x;  // 0..4351
  int bl = blockIdx.y;
  int b = bl >> 11, l = bl & 2047;
  float4 wv = *(const float4*)&conv_w[cc * 4];
  float wk[4] = {wv.x, wv.y, wv.z, wv.w};
  float acc = conv_b[cc];
  const short* pbase = xbc + (size_t)(b * SEQLEN) * CONVD + cc;
#pragma unroll
  for (int k = 0; k < 4; k++) {
    int ls = l - 3 + k;
    if (ls >= 0) acc += bf2f(pbase[(size_t)ls * CONVD]) * wk[k];
  }
  float sv = acc / (1.f + expf(-acc));
  xBCc[(size_t)bl * CONVD + cc] = f2bf(sv);
}

// ----------------------------------------------------- dt softplus (in-place)
__global__ __launch_bounds__(256) void dt_kernel(
    float* __restrict__ dtb, const float* __restrict__ dt_bias) {
  int idx = blockIdx.x * 256 + threadIdx.x;  // < 4096*64
  int hh = idx & 63;
  float v = dtb[idx] + dt_bias[hh];
  dtb[idx] = (v > 20.f) ? v : log1pf(expf(v));
}

// ---------------------------------------- per-chunk states (fp32 VALU)
// states[b,c,h,p,n] = sum_l x[l,p]*dt[l]*exp(Atot-Acum[l]) * B[l,n]  (bf16 out)
__global__ __launch_bounds__(256) void ssd_states_kernel(
    const short* __restrict__ xBCc, const float* __restrict__ dtp,
    const float* __restrict__ A_log, short* __restrict__ states,
    float* __restrict__ da_last) {
  const int blk = blockIdx.x;
  const int h = blk & 63, cc = (blk >> 6) & 7, b = blk >> 9;
  const int tid = threadIdx.x;
  __shared__ float dt_s[CSIZE], Acum[CSIZE], w_s[CSIZE];
  __shared__ float xw[64][64];
  __shared__ float Bt[64][NSTATE];
  const size_t row0 = (size_t)(b * SEQLEN + cc * CSIZE);
  dt_s[tid] = dtp[(row0 + tid) * NHEADS + h];
  __syncthreads();
  if (tid == 0) {
    float Aval = -expf(A_log[h]);
    float s = 0.f;
    for (int i = 0; i < CSIZE; i++) { s += dt_s[i]; Acum[i] = s * Aval; }
    da_last[(size_t)(b * NHEADS + h) * NCHUNK + cc] = Acum[CSIZE - 1];
  }
  __syncthreads();
  float total = Acum[CSIZE - 1];
  w_s[tid] = dt_s[tid] * expf(total - Acum[tid]);
  float acc[4][8];
  for (int a = 0; a < 4; a++) for (int j = 0; j < 8; j++) acc[a][j] = 0.f;
  const int pi = (tid & 15) * 4, ni = (tid >> 4) * 8;
  for (int lt = 0; lt < 4; lt++) {
    __syncthreads();
    for (int i = 0; i < 4; i++) {
      int idx = tid + i * 256;
      int r = idx >> 4, c4 = (idx & 15) << 2;
      short4 v = *(const short4*)&xBCc[(row0 + lt * 64 + r) * CONVD + h * PDIM + c4];
      float wl = w_s[lt * 64 + r];
      xw[r][c4 + 0] = bf2f(v.x) * wl;
      xw[r][c4 + 1] = bf2f(v.y) * wl;
      xw[r][c4 + 2] = bf2f(v.z) * wl;
      xw[r][c4 + 3] = bf2f(v.w) * wl;
    }
    for (int i = 0; i < 8; i++) {
      int idx = tid + i * 256;
      int r = idx >> 5, c4 = (idx & 31) << 2;
      short4 v = *(const short4*)&xBCc[(row0 + lt * 64 + r) * CONVD + DINNER + c4];
      Bt[r][c4 + 0] = bf2f(v.x);
      Bt[r][c4 + 1] = bf2f(v.y);
      Bt[r][c4 + 2] = bf2f(v.z);
      Bt[r][c4 + 3] = bf2f(v.w);
    }
    __syncthreads();
    for (int l = 0; l < 64; l++) {
      float4 xv = *(const float4*)&xw[l][pi];
      float4 b0 = *(const float4*)&Bt[l][ni];
      float4 b1 = *(const float4*)&Bt[l][ni + 4];
      float xa[4] = {xv.x, xv.y, xv.z, xv.w};
      float bb[8] = {b0.x, b0.y, b0.z, b0.w, b1.x, b1.y, b1.z, b1.w};
      for (int a = 0; a < 4; a++)
        for (int j = 0; j < 8; j++)
          acc[a][j] += xa[a] * bb[j];
    }
  }
  const size_t sbase = (((size_t)b * NCHUNK + cc) * NHEADS + h) * (PDIM * NSTATE);
  for (int a = 0; a < 4; a++)
    for (int j = 0; j < 8; j++)
      states[sbase + (size_t)(pi + a) * NSTATE + ni + j] = f2bf(acc[a][j]);
}

// ----------------------------------------------- 8-step chunk scan (in-place)
// states[c] becomes prev_state (state BEFORE chunk c); fp32 accum in regs.
__global__ __launch_bounds__(256) void scan_kernel(
    short* __restrict__ states, const float* __restrict__ da_last) {
  const int bh = blockIdx.x;  // b*64+h
  const int b = bh >> 6, h = bh & 63;
  const int tid = threadIdx.x;
  float prev[32];
  for (int i = 0; i < 32; i++) prev[i] = 0.f;
  for (int c = 0; c < NCHUNK; c++) {
    const size_t base = (((size_t)b * NCHUNK + c) * NHEADS + h) * (PDIM * NSTATE);
    const float d = expf(da_last[(size_t)bh * NCHUNK + c]);
    for (int i = 0; i < 32; i++) {
      size_t e = base + tid + i * 256;
      float s = bf2f(states[e]);
      states[e] = f2bf(prev[i]);
      prev[i] = prev[i] * d + s;
    }
  }
}

// ---------------------------------------------- SSD Y (MFMA core) -> bf16
// per (b,c,h): Y[l,p] = exp(Acum[l])*(C@prev^T) + (Lmat.*(C@B^T))@xdt + D*x
__global__ __launch_bounds__(256) void ssd_y_kernel(
    const short* __restrict__ xBCc, const float* __restrict__ dtp,
    const float* __restrict__ A_log, const float* __restrict__ D_param,
    const short* __restrict__ prevs, short* __restrict__ y) {
  const int blk = blockIdx.x;
  const int h = blk & 63, cc = (blk >> 6) & 7, b = blk >> 9;
  const int tid = threadIdx.x;
  const int lane = tid & 63, w = tid >> 6;
  const int lr = lane & 15, q = lane >> 4;
  __shared__ float dt_s[CSIZE];
  __shared__ float Acum[CSIZE];
  __shared__ short C_s[64][136];
  __shared__ short BP_s[64][136];
  __shared__ short xdtT[64][72];
  __shared__ short Mt[64][72];
  const size_t row0 = (size_t)(b * SEQLEN + cc * CSIZE);
  dt_s[tid] = dtp[(row0 + tid) * NHEADS + h];
  __syncthreads();
  if (tid == 0) {
    float Aval = -expf(A_log[h]);
    float s = 0.f;
    for (int i = 0; i < CSIZE; i++) { s += dt_s[i]; Acum[i] = s * Aval; }
  }
  const float Dh = D_param[h];
  const size_t prevbase = (((size_t)b * NCHUNK + cc) * NHEADS + h) * (PDIM * NSTATE);
  const int wl0 = w * 16;

  for (int lt = 0; lt < 4; lt++) {
    __syncthreads();
    // stage C tile + prev (both already bf16)
    for (int i = 0; i < 4; i++) {
      int idx = tid + i * 256;            // 1024 = 64 rows x 16 chunks of 8
      int r = idx >> 4, c8 = (idx & 15) << 3;
      *(s8v*)&C_s[r][c8] =
          *(const s8v*)&xBCc[(row0 + lt * 64 + r) * CONVD + DINNER + NSTATE + c8];
      *(s8v*)&BP_s[r][c8] = *(const s8v*)&prevs[prevbase + (size_t)r * NSTATE + c8];
    }
    __syncthreads();
    // phase A: acc = C @ prev^T  (K = n = 128)
    f4v acc[4];
    for (int j = 0; j < 4; j++) for (int r = 0; r < 4; r++) acc[j][r] = 0.f;
    for (int ks = 0; ks < 4; ks++) {
      s8v a = *(const s8v*)&C_s[wl0 + lr][ks * 32 + q * 8];
      for (int j = 0; j < 4; j++) {
        s8v bb = *(const s8v*)&BP_s[j * 16 + lr][ks * 32 + q * 8];
        acc[j] = mfma_bf16(a, bb, acc[j]);
      }
    }
    for (int r = 0; r < 4; r++) {
      float e = __expf(Acum[lt * 64 + wl0 + q * 4 + r]);
      for (int j = 0; j < 4; j++) acc[j][r] *= e;
    }
    // phase B: causal s-tiles
    for (int st = 0; st <= lt; st++) {
      __syncthreads();
      for (int i = 0; i < 4; i++) {
        int idx = tid + i * 256;
        int r = idx >> 4, c8 = (idx & 15) << 3;
        *(s8v*)&BP_s[r][c8] =
            *(const s8v*)&xBCc[(row0 + st * 64 + r) * CONVD + DINNER + c8];
      }
      for (int i = 0; i < 4; i++) {
        int idx = tid + i * 256;
        int r = idx >> 4, c4 = (idx & 15) << 2;
        float dtv = dt_s[st * 64 + r];
        short4 v = *(const short4*)&xBCc[(row0 + st * 64 + r) * CONVD + h * PDIM + c4];
        xdtT[c4 + 0][r] = f2bf(bf2f(v.x) * dtv);
        xdtT[c4 + 1][r] = f2bf(bf2f(v.y) * dtv);
        xdtT[c4 + 2][r] = f2bf(bf2f(v.z) * dtv);
        xdtT[c4 + 3][r] = f2bf(bf2f(v.w) * dtv);
      }
      __syncthreads();
      // S = C_tile @ B_s^T
      f4v sacc[4];
      for (int j = 0; j < 4; j++) for (int r = 0; r < 4; r++) sacc[j][r] = 0.f;
      for (int ks = 0; ks < 4; ks++) {
        s8v a = *(const s8v*)&C_s[wl0 + lr][ks * 32 + q * 8];
        for (int j = 0; j < 4; j++) {
          s8v bb = *(const s8v*)&BP_s[j * 16 + lr][ks * 32 + q * 8];
          sacc[j] = mfma_bf16(a, bb, sacc[j]);
        }
      }
      int lbase = lt * 64 + wl0 + q * 4;
      for (int j = 0; j < 4; j++) {
        int sg = st * 64 + j * 16 + lr;
        for (int r = 0; r < 4; r++) {
          int ll = lbase + r;
          float m = (sg <= ll) ? sacc[j][r] * __expf(Acum[ll] - Acum[sg]) : 0.f;
          Mt[wl0 + q * 4 + r][j * 16 + lr] = f2bf(m);
        }
      }
      __syncthreads();
      // Y += M @ xdt (K = s = 64)
      for (int ss2 = 0; ss2 < 2; ss2++) {
        s8v a = *(const s8v*)&Mt[wl0 + lr][ss2 * 32 + q * 8];
        for (int j = 0; j < 4; j++) {
          s8v bb = *(const s8v*)&xdtT[j * 16 + lr][ss2 * 32 + q * 8];
          acc[j] = mfma_bf16(a, bb, acc[j]);
        }
      }
    }
    // epilogue: + D*x, store bf16
    for (int j = 0; j < 4; j++) {
      for (int r = 0; r < 4; r++) {
        int ll = lt * 64 + wl0 + q * 4 + r;
        int p = j * 16 + lr;
        float xv = bf2f(xBCc[(row0 + ll) * CONVD + h * PDIM + p]);
        y[(row0 + ll) * DINNER + h * PDIM + p] = f2bf(acc[j][r] + Dh * xv);
      }
    }
  }
}

// -------------------------------------- gated RMSNorm -> bf16
__global__ __launch_bounds__(256) void norm_kernel(
    const short* __restrict__ y, const short* __restrict__ z,
    const float* __restrict__ norm_w, short* __restrict__ g) {
  int bl = blockIdx.x, tid = threadIdx.x;
  const short4* yrow = (const short4*)(y + (size_t)bl * DINNER);
  const short4* zrow = (const short4*)(z + (size_t)bl * DINNER);
  float gv[16];
  float ss = 0.f;
  for (int i = 0; i < 4; i++) {
    short4 yv = yrow[tid + i * 256];
    short4 zv = zrow[tid + i * 256];
    float zf[4] = {bf2f(zv.x), bf2f(zv.y), bf2f(zv.z), bf2f(zv.w)};
    float yf[4] = {bf2f(yv.x), bf2f(yv.y), bf2f(yv.z), bf2f(yv.w)};
    for (int t = 0; t < 4; t++) {
      float gg = yf[t] * (zf[t] / (1.f + expf(-zf[t])));
      gv[i * 4 + t] = gg;
      ss += gg * gg;
    }
  }
  for (int off = 32; off > 0; off >>= 1) ss += __shfl_down(ss, off);
  __shared__ float red[4];
  __shared__ float rsS;
  if ((tid & 63) == 0) red[tid >> 6] = ss;
  __syncthreads();
  if (tid == 0) rsS = rsqrtf((red[0] + red[1] + red[2] + red[3]) * (1.f / 4096.f) + 1e-5f);
  __syncthreads();
  float rs = rsS;
  for (int i = 0; i < 4; i++) {
    int j4 = (tid + i * 256) * 4;
    float4 nw = *(const float4*)&norm_w[j4];
    short4 o;
    o.x = f2bf(gv[i * 4 + 0] * rs * nw.x);
    o.y = f2bf(gv[i * 4 + 1] * rs * nw.y);
    o.z = f2bf(gv[i * 4 + 2] * rs * nw.z);
    o.w = f2bf(gv[i * 4 + 3] * rs * nw.w);
    *(short4*)&g[(size_t)bl * DINNER + j4] = o;
  }
}

extern "C" void kernel_launch(void* const* d_in, const int* in_sizes, int n_in,
                              void* d_out, int out_size, void* d_ws, size_t ws_size,
                              hipStream_t stream) {
  const float* hidden  = (const float*)d_in[0];
  const float* W_in    = (const float*)d_in[1];
  const float* conv_w  = (const float*)d_in[2];
  const float* conv_b  = (const float*)d_in[3];
  const float* dt_bias = (const float*)d_in[4];
  const float* A_log   = (const float*)d_in[5];
  const float* D_param = (const float*)d_in[6];
  const float* norm_w  = (const float*)d_in[7];
  const float* W_out   = (const float*)d_in[8];
  float* out = (float*)d_out;

  // ---- workspace arena (122,687,488 bytes), phase-overlapped regions ----
  char* ws = (char*)d_ws;
  // always-live
  short* z_bf  = (short*)(ws + 0);                     // [0, 33,554,432)
  float* dtb   = (float*)(ws + 33554432);              // [33.55M, 34.60M)
  float* da_l  = (float*)(ws + 34603008);              // 4 KB
  // region A: xBC_pre (GEMM1->conv), then y (ssd_y->norm)
  short* xbc_pre = (short*)(ws + 34607104);            // 35,651,584 B
  short* y_bf    = (short*)(ws + 34607104);            // 33,554,432 B (after conv)
  // region B: hid+win (casts->GEMM1), then xBCc / states / g / wout
  short* hid_bf  = (short*)(ws + 70258688);            // 16,777,216
  short* win_bf  = (short*)(ws + 87035904);            // 34,865,152 (end 121,901,056)
  short* xBCc    = (short*)(ws + 70258688);            // 35,651,584 (after GEMM1)
  short* states  = (short*)(ws + 105910272);           // 16,777,216 (after conv; end 122,687,488)
  short* g_bf    = (short*)(ws + 70258688);            // 33,554,432 (after ssd_y)
  short* wout_bf = (short*)(ws + 105910272);           // 16,777,216 (after ssd_y)
  if (ws_size < (size_t)122687488) return;

  cast_bf16_kernel<<<8192, 256, 0, stream>>>(hidden, hid_bf, 2097152);
  cast_bf16_kernel<<<17024, 256, 0, stream>>>(W_in, win_bf, 4358144);

  gemm1_kernel<<<dim3(67, 32), 256, 0, stream>>>(hid_bf, win_bf, z_bf, xbc_pre, dtb);

  conv_silu_kernel<<<dim3(17, 4096), 256, 0, stream>>>(xbc_pre, conv_w, conv_b, xBCc);
  dt_kernel<<<1024, 256, 0, stream>>>(dtb, dt_bias);

  ssd_states_kernel<<<1024, 256, 0, stream>>>(xBCc, dtb, A_log, states, da_l);
  scan_kernel<<<128, 256, 0, stream>>>(states, da_l);
  ssd_y_kernel<<<1024, 256, 0, stream>>>(xBCc, dtb, A_log, D_param, states, y_bf);

  norm_kernel<<<4096, 256, 0, stream>>>(y_bf, z_bf, norm_w, g_bf);
  cast_bf16_kernel<<<8192, 256, 0, stream>>>(W_out, wout_bf, 2097152);

  gemm_nt_bf16<<<dim3(16, 32), 256, 0, stream>>>(g_bf, wout_bf, out, 4096, 2048, 4096);
}

// Round 3
// 776.386 us; speedup vs baseline: 2.9463x; 2.9463x over previous
//
#include <hip/hip_runtime.h>

#define SEQLEN 2048
#define NHEADS 64
#define PDIM 64
#define NSTATE 128
#define CSIZE 256
#define NCHUNK 8
#define DINNER 4096
#define CONVD 4352
#define PROJD 8512

using s8v = __attribute__((ext_vector_type(8))) short;
using f4v = __attribute__((ext_vector_type(4))) float;
using bf8v = __attribute__((ext_vector_type(8))) __bf16;

__device__ __forceinline__ short f2bf(float x) {
  union { float f; unsigned u; } t; t.f = x;
  unsigned r = t.u + 0x7FFFu + ((t.u >> 16) & 1u);
  return (short)(r >> 16);
}
__device__ __forceinline__ float bf2f(short s) {
  union { unsigned u; float f; } t;
  t.u = ((unsigned)(unsigned short)s) << 16;
  return t.f;
}

__device__ __forceinline__ f4v mfma_bf16(s8v a, s8v b, f4v c) {
  return __builtin_amdgcn_mfma_f32_16x16x32_bf16(
      __builtin_bit_cast(bf8v, a), __builtin_bit_cast(bf8v, b), c, 0, 0, 0);
}

// async global->LDS, 16B per lane; LDS dest must be lane-contiguous
__device__ __forceinline__ void gll16(const void* g, void* l) {
  __builtin_amdgcn_global_load_lds(
      (const __attribute__((address_space(1))) unsigned*)g,
      (__attribute__((address_space(3))) unsigned*)l, 16, 0, 0);
}

// ---------------------------------------------------------------- casts
__global__ __launch_bounds__(256) void cast_bf16_kernel(
    const float* __restrict__ in, short* __restrict__ out, int n4) {
  int i = blockIdx.x * 256 + threadIdx.x;
  if (i < n4) {
    float4 v = ((const float4*)in)[i];
    short4 o;
    o.x = f2bf(v.x); o.y = f2bf(v.y); o.z = f2bf(v.z); o.w = f2bf(v.w);
    ((short4*)out)[i] = o;
  }
}

// ------------------------------------------- GEMM1 with split epilogue
// proj = hidden @ W_in^T ; cols [0,4096)->z bf16, [4096,8448)->xBC bf16,
// [8448,8512)->dt fp32.  M=4096, N=8512, K=2048. grid (67,32).
__global__ __launch_bounds__(256) void gemm1_kernel(
    const short* __restrict__ A, const short* __restrict__ B,
    short* __restrict__ z, short* __restrict__ xbc, float* __restrict__ dtb) {
  const int K = 2048;
  const int tn0 = blockIdx.x * 128;
  const int tm0 = blockIdx.y * 128;
  __shared__ short As[128 * 32];   // unpadded: required by global_load_lds
  __shared__ short Bs[128 * 32];
  __shared__ short Cs[128 * 136];  // epilogue transpose, stride 272B (16B-aligned)
  const int tid = threadIdx.x;
  const int lane = tid & 63, wid = tid >> 6;
  const int wm = (wid >> 1) * 64, wn = (wid & 1) * 64;
  const int lr = lane & 15, q = lane >> 4;
  f4v acc[4][4];
  for (int i = 0; i < 4; i++)
    for (int j = 0; j < 4; j++)
      for (int r = 0; r < 4; r++) acc[i][j][r] = 0.f;

  for (int k0 = 0; k0 < K; k0 += 32) {
    __syncthreads();
    for (int it = 0; it < 2; it++) {
      int ci = it * 256 + tid;           // 512 chunks of 16B per matrix
      int row = ci >> 2, col8 = (ci & 3) << 3;
      gll16(&A[(size_t)(tm0 + row) * K + k0 + col8], &As[ci * 8]);
      gll16(&B[(size_t)(tn0 + row) * K + k0 + col8], &Bs[ci * 8]);
    }
    __syncthreads();
    s8v af[4], bfr[4];
    for (int i = 0; i < 4; i++) af[i]  = *(const s8v*)&As[(wm + i * 16 + lr) * 32 + q * 8];
    for (int j = 0; j < 4; j++) bfr[j] = *(const s8v*)&Bs[(wn + j * 16 + lr) * 32 + q * 8];
    for (int i = 0; i < 4; i++)
      for (int j = 0; j < 4; j++)
        acc[i][j] = mfma_bf16(af[i], bfr[j], acc[i][j]);
  }

  if (tn0 < 8448) {  // z or xbc region (tile-aligned split at 4096 and 8448)
    for (int i = 0; i < 4; i++)
      for (int j = 0; j < 4; j++)
        for (int r = 0; r < 4; r++)
          Cs[(wm + i * 16 + q * 4 + r) * 136 + wn + j * 16 + lr] = f2bf(acc[i][j][r]);
    __syncthreads();
    short* outp; int rowstride, colbase;
    if (tn0 < DINNER) { outp = z;   rowstride = DINNER; colbase = tn0; }
    else              { outp = xbc; rowstride = CONVD;  colbase = tn0 - DINNER; }
    for (int ps = 0; ps < 8; ps++) {
      int r = ps * 16 + (tid >> 4);
      int c8 = (tid & 15) * 8;
      s8v v = *(const s8v*)&Cs[r * 136 + c8];
      *(s8v*)&outp[(size_t)(tm0 + r) * rowstride + colbase + c8] = v;
    }
  } else {  // dt tile: 64 valid cols, fp32 out (keep full precision)
    for (int i = 0; i < 4; i++)
      for (int j = 0; j < 4; j++) {
        int c0 = tn0 + wn + j * 16 + lr;
        if (c0 < PROJD)
          for (int r = 0; r < 4; r++)
            dtb[(size_t)(tm0 + wm + i * 16 + q * 4 + r) * NHEADS + (c0 - 8448)] =
                acc[i][j][r];
      }
  }
}

// ------------------------------------------------- GEMM2 (fp32 out, exact dims)
// out = g @ W_out^T. M=4096, N=2048, K=4096. grid (16,32).
__global__ __launch_bounds__(256) void gemm_nt_bf16(
    const short* __restrict__ A, const short* __restrict__ B,
    float* __restrict__ C, int M, int N, int K) {
  const int tn0 = blockIdx.x * 128;
  const int tm0 = blockIdx.y * 128;
  __shared__ short As[128 * 32];
  __shared__ short Bs[128 * 32];
  const int tid = threadIdx.x;
  const int lane = tid & 63, wid = tid >> 6;
  const int wm = (wid >> 1) * 64, wn = (wid & 1) * 64;
  const int lr = lane & 15, q = lane >> 4;
  f4v acc[4][4];
  for (int i = 0; i < 4; i++)
    for (int j = 0; j < 4; j++)
      for (int r = 0; r < 4; r++) acc[i][j][r] = 0.f;

  for (int k0 = 0; k0 < K; k0 += 32) {
    __syncthreads();
    for (int it = 0; it < 2; it++) {
      int ci = it * 256 + tid;
      int row = ci >> 2, col8 = (ci & 3) << 3;
      gll16(&A[(size_t)(tm0 + row) * K + k0 + col8], &As[ci * 8]);
      gll16(&B[(size_t)(tn0 + row) * K + k0 + col8], &Bs[ci * 8]);
    }
    __syncthreads();
    s8v af[4], bfr[4];
    for (int i = 0; i < 4; i++) af[i]  = *(const s8v*)&As[(wm + i * 16 + lr) * 32 + q * 8];
    for (int j = 0; j < 4; j++) bfr[j] = *(const s8v*)&Bs[(wn + j * 16 + lr) * 32 + q * 8];
    for (int i = 0; i < 4; i++)
      for (int j = 0; j < 4; j++)
        acc[i][j] = mfma_bf16(af[i], bfr[j], acc[i][j]);
  }
  // fp32 dword scatter: 64B/quarter-wave segments (m97-proven OK)
  for (int i = 0; i < 4; i++)
    for (int j = 0; j < 4; j++) {
      int r0 = tm0 + wm + i * 16 + q * 4;
      int c0 = tn0 + wn + j * 16 + lr;
      for (int r = 0; r < 4; r++)
        C[(size_t)(r0 + r) * N + c0] = acc[i][j][r];
    }
}

// ------------------------------------------------ depthwise conv + SiLU
__global__ __launch_bounds__(256) void conv_silu_kernel(
    const short* __restrict__ xbc, const float* __restrict__ conv_w,
    const float* __restrict__ conv_b, short* __restrict__ xBCc) {
  int cc = blockIdx.x * 256 + threadIdx.x;  // 0..4351
  int bl = blockIdx.y;
  int b = bl >> 11, l = bl & 2047;
  float4 wv = *(const float4*)&conv_w[cc * 4];
  float wk[4] = {wv.x, wv.y, wv.z, wv.w};
  float acc = conv_b[cc];
  const short* pbase = xbc + (size_t)(b * SEQLEN) * CONVD + cc;
#pragma unroll
  for (int k = 0; k < 4; k++) {
    int ls = l - 3 + k;
    if (ls >= 0) acc += bf2f(pbase[(size_t)ls * CONVD]) * wk[k];
  }
  float sv = acc / (1.f + expf(-acc));
  xBCc[(size_t)bl * CONVD + cc] = f2bf(sv);
}

// ----------------------------------------------------- dt softplus (in-place)
__global__ __launch_bounds__(256) void dt_kernel(
    float* __restrict__ dtb, const float* __restrict__ dt_bias) {
  int idx = blockIdx.x * 256 + threadIdx.x;  // < 4096*64
  int hh = idx & 63;
  float v = dtb[idx] + dt_bias[hh];
  dtb[idx] = (v > 20.f) ? v : log1pf(expf(v));
}

// ---------------------------------------- per-chunk states (fp32 VALU)
__global__ __launch_bounds__(256) void ssd_states_kernel(
    const short* __restrict__ xBCc, const float* __restrict__ dtp,
    const float* __restrict__ A_log, short* __restrict__ states,
    float* __restrict__ da_last) {
  const int blk = blockIdx.x;
  const int h = blk & 63, cc = (blk >> 6) & 7, b = blk >> 9;
  const int tid = threadIdx.x;
  __shared__ float dt_s[CSIZE], Acum[CSIZE], w_s[CSIZE];
  __shared__ float xw[64][64];
  __shared__ float Bt[64][NSTATE];
  const size_t row0 = (size_t)(b * SEQLEN + cc * CSIZE);
  dt_s[tid] = dtp[(row0 + tid) * NHEADS + h];
  __syncthreads();
  if (tid == 0) {
    float Aval = -expf(A_log[h]);
    float s = 0.f;
    for (int i = 0; i < CSIZE; i++) { s += dt_s[i]; Acum[i] = s * Aval; }
    da_last[(size_t)(b * NHEADS + h) * NCHUNK + cc] = Acum[CSIZE - 1];
  }
  __syncthreads();
  float total = Acum[CSIZE - 1];
  w_s[tid] = dt_s[tid] * expf(total - Acum[tid]);
  float acc[4][8];
  for (int a = 0; a < 4; a++) for (int j = 0; j < 8; j++) acc[a][j] = 0.f;
  const int pi = (tid & 15) * 4, ni = (tid >> 4) * 8;
  for (int lt = 0; lt < 4; lt++) {
    __syncthreads();
    for (int i = 0; i < 4; i++) {
      int idx = tid + i * 256;
      int r = idx >> 4, c4 = (idx & 15) << 2;
      short4 v = *(const short4*)&xBCc[(row0 + lt * 64 + r) * CONVD + h * PDIM + c4];
      float wl = w_s[lt * 64 + r];
      xw[r][c4 + 0] = bf2f(v.x) * wl;
      xw[r][c4 + 1] = bf2f(v.y) * wl;
      xw[r][c4 + 2] = bf2f(v.z) * wl;
      xw[r][c4 + 3] = bf2f(v.w) * wl;
    }
    for (int i = 0; i < 8; i++) {
      int idx = tid + i * 256;
      int r = idx >> 5, c4 = (idx & 31) << 2;
      short4 v = *(const short4*)&xBCc[(row0 + lt * 64 + r) * CONVD + DINNER + c4];
      Bt[r][c4 + 0] = bf2f(v.x);
      Bt[r][c4 + 1] = bf2f(v.y);
      Bt[r][c4 + 2] = bf2f(v.z);
      Bt[r][c4 + 3] = bf2f(v.w);
    }
    __syncthreads();
    for (int l = 0; l < 64; l++) {
      float4 xv = *(const float4*)&xw[l][pi];
      float4 b0 = *(const float4*)&Bt[l][ni];
      float4 b1 = *(const float4*)&Bt[l][ni + 4];
      float xa[4] = {xv.x, xv.y, xv.z, xv.w};
      float bb[8] = {b0.x, b0.y, b0.z, b0.w, b1.x, b1.y, b1.z, b1.w};
      for (int a = 0; a < 4; a++)
        for (int j = 0; j < 8; j++)
          acc[a][j] += xa[a] * bb[j];
    }
  }
  const size_t sbase = (((size_t)b * NCHUNK + cc) * NHEADS + h) * (PDIM * NSTATE);
  for (int a = 0; a < 4; a++) {
    short o[8];
    for (int j = 0; j < 8; j++) o[j] = f2bf(acc[a][j]);
    *(s8v*)&states[sbase + (size_t)(pi + a) * NSTATE + ni] = *(const s8v*)o;
  }
}

// ----------------------------------------------- 8-step chunk scan (in-place)
__global__ __launch_bounds__(256) void scan_kernel(
    short* __restrict__ states, const float* __restrict__ da_last) {
  const int bh = blockIdx.x;  // b*64+h
  const int b = bh >> 6, h = bh & 63;
  const int tid = threadIdx.x;
  float prev[32];
  for (int i = 0; i < 32; i++) prev[i] = 0.f;
  for (int c = 0; c < NCHUNK; c++) {
    const size_t base = (((size_t)b * NCHUNK + c) * NHEADS + h) * (PDIM * NSTATE);
    const float d = expf(da_last[(size_t)bh * NCHUNK + c]);
    for (int i = 0; i < 32; i++) {
      size_t e = base + tid + i * 256;
      float s = bf2f(states[e]);
      states[e] = f2bf(prev[i]);
      prev[i] = prev[i] * d + s;
    }
  }
}

// ---------------------------------------------- SSD Y (MFMA core) -> bf16
__global__ __launch_bounds__(256) void ssd_y_kernel(
    const short* __restrict__ xBCc, const float* __restrict__ dtp,
    const float* __restrict__ A_log, const float* __restrict__ D_param,
    const short* __restrict__ prevs, short* __restrict__ y) {
  const int blk = blockIdx.x;
  const int h = blk & 63, cc = (blk >> 6) & 7, b = blk >> 9;
  const int tid = threadIdx.x;
  const int lane = tid & 63, w = tid >> 6;
  const int lr = lane & 15, q = lane >> 4;
  __shared__ float dt_s[CSIZE];
  __shared__ float Acum[CSIZE];
  __shared__ short C_s[64][136];
  __shared__ short BP_s[64][136];
  __shared__ short xdtT[64][72];
  __shared__ short Mt[64][72];
  const size_t row0 = (size_t)(b * SEQLEN + cc * CSIZE);
  dt_s[tid] = dtp[(row0 + tid) * NHEADS + h];
  __syncthreads();
  if (tid == 0) {
    float Aval = -expf(A_log[h]);
    float s = 0.f;
    for (int i = 0; i < CSIZE; i++) { s += dt_s[i]; Acum[i] = s * Aval; }
  }
  const float Dh = D_param[h];
  const size_t prevbase = (((size_t)b * NCHUNK + cc) * NHEADS + h) * (PDIM * NSTATE);
  const int wl0 = w * 16;

  for (int lt = 0; lt < 4; lt++) {
    __syncthreads();
    for (int i = 0; i < 4; i++) {
      int idx = tid + i * 256;
      int r = idx >> 4, c8 = (idx & 15) << 3;
      *(s8v*)&C_s[r][c8] =
          *(const s8v*)&xBCc[(row0 + lt * 64 + r) * CONVD + DINNER + NSTATE + c8];
      *(s8v*)&BP_s[r][c8] = *(const s8v*)&prevs[prevbase + (size_t)r * NSTATE + c8];
    }
    __syncthreads();
    // phase A: acc = C @ prev^T  (K = n = 128)
    f4v acc[4];
    for (int j = 0; j < 4; j++) for (int r = 0; r < 4; r++) acc[j][r] = 0.f;
    for (int ks = 0; ks < 4; ks++) {
      s8v a = *(const s8v*)&C_s[wl0 + lr][ks * 32 + q * 8];
      for (int j = 0; j < 4; j++) {
        s8v bb = *(const s8v*)&BP_s[j * 16 + lr][ks * 32 + q * 8];
        acc[j] = mfma_bf16(a, bb, acc[j]);
      }
    }
    for (int r = 0; r < 4; r++) {
      float e = __expf(Acum[lt * 64 + wl0 + q * 4 + r]);
      for (int j = 0; j < 4; j++) acc[j][r] *= e;
    }
    // phase B: causal s-tiles
    for (int st = 0; st <= lt; st++) {
      __syncthreads();
      for (int i = 0; i < 4; i++) {
        int idx = tid + i * 256;
        int r = idx >> 4, c8 = (idx & 15) << 3;
        *(s8v*)&BP_s[r][c8] =
            *(const s8v*)&xBCc[(row0 + st * 64 + r) * CONVD + DINNER + c8];
      }
      for (int i = 0; i < 4; i++) {
        int idx = tid + i * 256;
        int r = idx >> 4, c4 = (idx & 15) << 2;
        float dtv = dt_s[st * 64 + r];
        short4 v = *(const short4*)&xBCc[(row0 + st * 64 + r) * CONVD + h * PDIM + c4];
        xdtT[c4 + 0][r] = f2bf(bf2f(v.x) * dtv);
        xdtT[c4 + 1][r] = f2bf(bf2f(v.y) * dtv);
        xdtT[c4 + 2][r] = f2bf(bf2f(v.z) * dtv);
        xdtT[c4 + 3][r] = f2bf(bf2f(v.w) * dtv);
      }
      __syncthreads();
      f4v sacc[4];
      for (int j = 0; j < 4; j++) for (int r = 0; r < 4; r++) sacc[j][r] = 0.f;
      for (int ks = 0; ks < 4; ks++) {
        s8v a = *(const s8v*)&C_s[wl0 + lr][ks * 32 + q * 8];
        for (int j = 0; j < 4; j++) {
          s8v bb = *(const s8v*)&BP_s[j * 16 + lr][ks * 32 + q * 8];
          sacc[j] = mfma_bf16(a, bb, sacc[j]);
        }
      }
      int lbase = lt * 64 + wl0 + q * 4;
      for (int j = 0; j < 4; j++) {
        int sg = st * 64 + j * 16 + lr;
        for (int r = 0; r < 4; r++) {
          int ll = lbase + r;
          float m = (sg <= ll) ? sacc[j][r] * __expf(Acum[ll] - Acum[sg]) : 0.f;
          Mt[wl0 + q * 4 + r][j * 16 + lr] = f2bf(m);
        }
      }
      __syncthreads();
      for (int ss2 = 0; ss2 < 2; ss2++) {
        s8v a = *(const s8v*)&Mt[wl0 + lr][ss2 * 32 + q * 8];
        for (int j = 0; j < 4; j++) {
          s8v bb = *(const s8v*)&xdtT[j * 16 + lr][ss2 * 32 + q * 8];
          acc[j] = mfma_bf16(a, bb, acc[j]);
        }
      }
    }
    // epilogue: fold D*x, transpose via Mt (wave-own rows), coalesced store
    for (int j = 0; j < 4; j++)
      for (int r = 0; r < 4; r++) {
        int lrow = wl0 + q * 4 + r;
        int ll = lt * 64 + lrow;
        int p = j * 16 + lr;
        float xv = bf2f(xBCc[(row0 + ll) * CONVD + h * PDIM + p]);
        Mt[lrow][p] = f2bf(acc[j][r] + Dh * xv);
      }
    __syncthreads();
    for (int ps = 0; ps < 2; ps++) {
      int r = ps * 32 + (tid >> 3);
      int c8 = (tid & 7) * 8;
      s8v v = *(const s8v*)&Mt[r][c8];
      *(s8v*)&y[(row0 + lt * 64 + r) * DINNER + h * PDIM + c8] = v;
    }
  }
}

// -------------------------------------- gated RMSNorm -> bf16
__global__ __launch_bounds__(256) void norm_kernel(
    const short* __restrict__ y, const short* __restrict__ z,
    const float* __restrict__ norm_w, short* __restrict__ g) {
  int bl = blockIdx.x, tid = threadIdx.x;
  const short4* yrow = (const short4*)(y + (size_t)bl * DINNER);
  const short4* zrow = (const short4*)(z + (size_t)bl * DINNER);
  float gv[16];
  float ss = 0.f;
  for (int i = 0; i < 4; i++) {
    short4 yv = yrow[tid + i * 256];
    short4 zv = zrow[tid + i * 256];
    float zf[4] = {bf2f(zv.x), bf2f(zv.y), bf2f(zv.z), bf2f(zv.w)};
    float yf[4] = {bf2f(yv.x), bf2f(yv.y), bf2f(yv.z), bf2f(yv.w)};
    for (int t = 0; t < 4; t++) {
      float gg = yf[t] * (zf[t] / (1.f + expf(-zf[t])));
      gv[i * 4 + t] = gg;
      ss += gg * gg;
    }
  }
  for (int off = 32; off > 0; off >>= 1) ss += __shfl_down(ss, off);
  __shared__ float red[4];
  __shared__ float rsS;
  if ((tid & 63) == 0) red[tid >> 6] = ss;
  __syncthreads();
  if (tid == 0) rsS = rsqrtf((red[0] + red[1] + red[2] + red[3]) * (1.f / 4096.f) + 1e-5f);
  __syncthreads();
  float rs = rsS;
  for (int i = 0; i < 4; i++) {
    int j4 = (tid + i * 256) * 4;
    float4 nw = *(const float4*)&norm_w[j4];
    short4 o;
    o.x = f2bf(gv[i * 4 + 0] * rs * nw.x);
    o.y = f2bf(gv[i * 4 + 1] * rs * nw.y);
    o.z = f2bf(gv[i * 4 + 2] * rs * nw.z);
    o.w = f2bf(gv[i * 4 + 3] * rs * nw.w);
    *(short4*)&g[(size_t)bl * DINNER + j4] = o;
  }
}

extern "C" void kernel_launch(void* const* d_in, const int* in_sizes, int n_in,
                              void* d_out, int out_size, void* d_ws, size_t ws_size,
                              hipStream_t stream) {
  const float* hidden  = (const float*)d_in[0];
  const float* W_in    = (const float*)d_in[1];
  const float* conv_w  = (const float*)d_in[2];
  const float* conv_b  = (const float*)d_in[3];
  const float* dt_bias = (const float*)d_in[4];
  const float* A_log   = (const float*)d_in[5];
  const float* D_param = (const float*)d_in[6];
  const float* norm_w  = (const float*)d_in[7];
  const float* W_out   = (const float*)d_in[8];
  float* out = (float*)d_out;

  // ---- workspace arena (122,687,488 bytes), phase-overlapped regions ----
  char* ws = (char*)d_ws;
  short* z_bf  = (short*)(ws + 0);                     // 33,554,432
  float* dtb   = (float*)(ws + 33554432);              //  1,048,576
  float* da_l  = (float*)(ws + 34603008);              //  4 KB
  short* xbc_pre = (short*)(ws + 34607104);            // 35,651,584 (GEMM1->conv)
  short* y_bf    = (short*)(ws + 34607104);            // 33,554,432 (ssd_y->norm)
  short* hid_bf  = (short*)(ws + 70258688);            // 16,777,216 (casts->GEMM1)
  short* win_bf  = (short*)(ws + 87035904);            // 34,865,152 (casts->GEMM1)
  short* xBCc    = (short*)(ws + 70258688);            // 35,651,584 (conv->ssd)
  short* states  = (short*)(ws + 105910272);           // 16,777,216 (ssd)
  short* g_bf    = (short*)(ws + 70258688);            // 33,554,432 (norm->GEMM2)
  short* wout_bf = (short*)(ws + 105910272);           // 16,777,216 (cast->GEMM2)
  if (ws_size < (size_t)122687488) return;

  cast_bf16_kernel<<<8192, 256, 0, stream>>>(hidden, hid_bf, 2097152);
  cast_bf16_kernel<<<17024, 256, 0, stream>>>(W_in, win_bf, 4358144);

  gemm1_kernel<<<dim3(67, 32), 256, 0, stream>>>(hid_bf, win_bf, z_bf, xbc_pre, dtb);

  conv_silu_kernel<<<dim3(17, 4096), 256, 0, stream>>>(xbc_pre, conv_w, conv_b, xBCc);
  dt_kernel<<<1024, 256, 0, stream>>>(dtb, dt_bias);

  ssd_states_kernel<<<1024, 256, 0, stream>>>(xBCc, dtb, A_log, states, da_l);
  scan_kernel<<<128, 256, 0, stream>>>(states, da_l);
  ssd_y_kernel<<<1024, 256, 0, stream>>>(xBCc, dtb, A_log, D_param, states, y_bf);

  norm_kernel<<<4096, 256, 0, stream>>>(y_bf, z_bf, norm_w, g_bf);
  cast_bf16_kernel<<<8192, 256, 0, stream>>>(W_out, wout_bf, 2097152);

  gemm_nt_bf16<<<dim3(16, 32), 256, 0, stream>>>(g_bf, wout_bf, out, 4096, 2048, 4096);
}

// Round 4
// 697.963 us; speedup vs baseline: 3.2773x; 1.1124x over previous
//
#include <hip/hip_runtime.h>

#define SEQLEN 2048
#define NHEADS 64
#define PDIM 64
#define NSTATE 128
#define CSIZE 256
#define NCHUNK 8
#define DINNER 4096
#define CONVD 4352
#define PROJD 8512

using s8v = __attribute__((ext_vector_type(8))) short;
using f4v = __attribute__((ext_vector_type(4))) float;
using bf8v = __attribute__((ext_vector_type(8))) __bf16;

__device__ __forceinline__ short f2bf(float x) {
  union { float f; unsigned u; } t; t.f = x;
  unsigned r = t.u + 0x7FFFu + ((t.u >> 16) & 1u);
  return (short)(r >> 16);
}
__device__ __forceinline__ float bf2f(short s) {
  union { unsigned u; float f; } t;
  t.u = ((unsigned)(unsigned short)s) << 16;
  return t.f;
}

__device__ __forceinline__ f4v mfma_bf16(s8v a, s8v b, f4v c) {
  return __builtin_amdgcn_mfma_f32_16x16x32_bf16(
      __builtin_bit_cast(bf8v, a), __builtin_bit_cast(bf8v, b), c, 0, 0, 0);
}

// async global->LDS, 16B per lane; LDS dest must be lane-contiguous
__device__ __forceinline__ void gll16(const void* g, void* l) {
  __builtin_amdgcn_global_load_lds(
      (const __attribute__((address_space(1))) unsigned*)g,
      (__attribute__((address_space(3))) unsigned*)l, 16, 0, 0);
}

// ---------------------------------------------------------------- casts
__global__ __launch_bounds__(256) void cast_bf16_kernel(
    const float* __restrict__ in, short* __restrict__ out, int n4) {
  int i = blockIdx.x * 256 + threadIdx.x;
  if (i < n4) {
    float4 v = ((const float4*)in)[i];
    short4 o;
    o.x = f2bf(v.x); o.y = f2bf(v.y); o.z = f2bf(v.z); o.w = f2bf(v.w);
    ((short4*)out)[i] = o;
  }
}

// ------------------------------------------- GEMM1 with split epilogue
// proj = hidden @ W_in^T ; cols [0,4096)->z bf16, [4096,8448)->xBC bf16,
// [8448,8512)->dt fp32.  M=4096, N=8512, K=2048. 1D grid 2144, 4-high panels.
__global__ __launch_bounds__(256, 4) void gemm1_kernel(
    const short* __restrict__ A, const short* __restrict__ B,
    short* __restrict__ z, short* __restrict__ xbc, float* __restrict__ dtb) {
  const int K = 2048;
  // panel remap: 4 consecutive y share each x (B-tile L2 reuse)
  const int bid = blockIdx.x;
  const int panel = bid / (67 * 4), rem = bid % (67 * 4);
  const int bx = rem >> 2, by = panel * 4 + (rem & 3);
  const int tn0 = bx * 128, tm0 = by * 128;
  // union: As(4096)+Bs(4096) shorts live in K-loop; Cs(8704) live in epilogue
  __shared__ alignas(16) short lds[8704];
  short* As = lds;
  short* Bs = lds + 4096;
  short* Cs = lds;
  const int tid = threadIdx.x;
  const int lane = tid & 63, wid = tid >> 6;
  const int wm = (wid >> 1) * 64, wn = (wid & 1) * 64;
  const int lr = lane & 15, q = lane >> 4;
  const int fA = (lr & 3) ^ ((lr >> 2) & 3);  // fragment swizzle (lr-only)
  const int qs = (q ^ fA) * 8;
  f4v acc[4][4];
  for (int i = 0; i < 4; i++)
    for (int j = 0; j < 4; j++)
      for (int r = 0; r < 4; r++) acc[i][j][r] = 0.f;

  for (int k0 = 0; k0 < K; k0 += 32) {
    __syncthreads();
    for (int it = 0; it < 2; it++) {
      int ci = it * 256 + tid;           // 512 chunks of 16B per matrix
      int row = ci >> 2;
      int cg = ((ci & 3) ^ (row & 3) ^ ((row >> 2) & 3)) << 3;  // swizzled src col
      gll16(&A[(size_t)(tm0 + row) * K + k0 + cg], &As[ci * 8]);
      gll16(&B[(size_t)(tn0 + row) * K + k0 + cg], &Bs[ci * 8]);
    }
    __syncthreads();
    s8v af[4], bfr[4];
    for (int i = 0; i < 4; i++) af[i]  = *(const s8v*)&As[(wm + i * 16 + lr) * 32 + qs];
    for (int j = 0; j < 4; j++) bfr[j] = *(const s8v*)&Bs[(wn + j * 16 + lr) * 32 + qs];
    for (int i = 0; i < 4; i++)
      for (int j = 0; j < 4; j++)
        acc[i][j] = mfma_bf16(af[i], bfr[j], acc[i][j]);
  }
  __syncthreads();  // all ds_reads done before Cs overwrites As/Bs

  if (tn0 < 8448) {  // z or xbc region (tile-aligned split at 4096 and 8448)
    short* outp; int rowstride, colbase;
    if (tn0 < DINNER) { outp = z;   rowstride = DINNER; colbase = tn0; }
    else              { outp = xbc; rowstride = CONVD;  colbase = tn0 - DINNER; }
    for (int hh = 0; hh < 2; hh++) {  // two 64-row halves through Cs
      if ((wid >> 1) == hh) {
        for (int i = 0; i < 4; i++)
          for (int j = 0; j < 4; j++)
            for (int r = 0; r < 4; r++)
              Cs[(i * 16 + q * 4 + r) * 136 + wn + j * 16 + lr] = f2bf(acc[i][j][r]);
      }
      __syncthreads();
      for (int ps = 0; ps < 4; ps++) {
        int idx = ps * 256 + tid;
        int r = idx >> 4, c8 = (idx & 15) * 8;
        s8v v = *(const s8v*)&Cs[r * 136 + c8];
        *(s8v*)&outp[(size_t)(tm0 + hh * 64 + r) * rowstride + colbase + c8] = v;
      }
      __syncthreads();
    }
  } else {  // dt tile: 64 valid cols, fp32 out (keep full precision)
    for (int i = 0; i < 4; i++)
      for (int j = 0; j < 4; j++) {
        int c0 = tn0 + wn + j * 16 + lr;
        if (c0 < PROJD)
          for (int r = 0; r < 4; r++)
            dtb[(size_t)(tm0 + wm + i * 16 + q * 4 + r) * NHEADS + (c0 - 8448)] =
                acc[i][j][r];
      }
  }
}

// ------------------------------------------------- GEMM2 (fp32 out)
// out = g @ W_out^T. M=4096, N=2048, K=4096. 1D grid 512, 4-high panels.
__global__ __launch_bounds__(256, 4) void gemm_nt_bf16(
    const short* __restrict__ A, const short* __restrict__ B,
    float* __restrict__ C, int M, int N, int K) {
  const int nbx = N >> 7;
  const int bid = blockIdx.x;
  const int panel = bid / (nbx * 4), rem = bid % (nbx * 4);
  const int bx = rem >> 2, by = panel * 4 + (rem & 3);
  const int tn0 = bx * 128, tm0 = by * 128;
  __shared__ alignas(16) short As[128 * 32];
  __shared__ alignas(16) short Bs[128 * 32];
  const int tid = threadIdx.x;
  const int lane = tid & 63, wid = tid >> 6;
  const int wm = (wid >> 1) * 64, wn = (wid & 1) * 64;
  const int lr = lane & 15, q = lane >> 4;
  const int fA = (lr & 3) ^ ((lr >> 2) & 3);
  const int qs = (q ^ fA) * 8;
  f4v acc[4][4];
  for (int i = 0; i < 4; i++)
    for (int j = 0; j < 4; j++)
      for (int r = 0; r < 4; r++) acc[i][j][r] = 0.f;

  for (int k0 = 0; k0 < K; k0 += 32) {
    __syncthreads();
    for (int it = 0; it < 2; it++) {
      int ci = it * 256 + tid;
      int row = ci >> 2;
      int cg = ((ci & 3) ^ (row & 3) ^ ((row >> 2) & 3)) << 3;
      gll16(&A[(size_t)(tm0 + row) * K + k0 + cg], &As[ci * 8]);
      gll16(&B[(size_t)(tn0 + row) * K + k0 + cg], &Bs[ci * 8]);
    }
    __syncthreads();
    s8v af[4], bfr[4];
    for (int i = 0; i < 4; i++) af[i]  = *(const s8v*)&As[(wm + i * 16 + lr) * 32 + qs];
    for (int j = 0; j < 4; j++) bfr[j] = *(const s8v*)&Bs[(wn + j * 16 + lr) * 32 + qs];
    for (int i = 0; i < 4; i++)
      for (int j = 0; j < 4; j++)
        acc[i][j] = mfma_bf16(af[i], bfr[j], acc[i][j]);
  }
  // fp32 dword scatter: 64B/quarter-wave segments (m97-proven OK)
  for (int i = 0; i < 4; i++)
    for (int j = 0; j < 4; j++) {
      int r0 = tm0 + wm + i * 16 + q * 4;
      int c0 = tn0 + wn + j * 16 + lr;
      for (int r = 0; r < 4; r++)
        C[(size_t)(r0 + r) * N + c0] = acc[i][j][r];
    }
}

// ------------------------------------------------ depthwise conv + SiLU
__global__ __launch_bounds__(256) void conv_silu_kernel(
    const short* __restrict__ xbc, const float* __restrict__ conv_w,
    const float* __restrict__ conv_b, short* __restrict__ xBCc) {
  int cc = blockIdx.x * 256 + threadIdx.x;  // 0..4351
  int bl = blockIdx.y;
  int b = bl >> 11, l = bl & 2047;
  float4 wv = *(const float4*)&conv_w[cc * 4];
  float wk[4] = {wv.x, wv.y, wv.z, wv.w};
  float acc = conv_b[cc];
  const short* pbase = xbc + (size_t)(b * SEQLEN) * CONVD + cc;
#pragma unroll
  for (int k = 0; k < 4; k++) {
    int ls = l - 3 + k;
    if (ls >= 0) acc += bf2f(pbase[(size_t)ls * CONVD]) * wk[k];
  }
  float sv = acc / (1.f + expf(-acc));
  xBCc[(size_t)bl * CONVD + cc] = f2bf(sv);
}

// ----------------------------------------------------- dt softplus (in-place)
__global__ __launch_bounds__(256) void dt_kernel(
    float* __restrict__ dtb, const float* __restrict__ dt_bias) {
  int idx = blockIdx.x * 256 + threadIdx.x;  // < 4096*64
  int hh = idx & 63;
  float v = dtb[idx] + dt_bias[hh];
  dtb[idx] = (v > 20.f) ? v : log1pf(expf(v));
}

// ---------------------------------------- per-chunk states (fp32 VALU)
__global__ __launch_bounds__(256) void ssd_states_kernel(
    const short* __restrict__ xBCc, const float* __restrict__ dtp,
    const float* __restrict__ A_log, short* __restrict__ states,
    float* __restrict__ da_last) {
  const int blk = blockIdx.x;
  const int h = blk & 63, cc = (blk >> 6) & 7, b = blk >> 9;
  const int tid = threadIdx.x;
  __shared__ float dt_s[CSIZE], Acum[CSIZE], w_s[CSIZE];
  __shared__ float xw[64][64];
  __shared__ float Bt[64][NSTATE];
  const size_t row0 = (size_t)(b * SEQLEN + cc * CSIZE);
  dt_s[tid] = dtp[(row0 + tid) * NHEADS + h];
  __syncthreads();
  if (tid == 0) {
    float Aval = -expf(A_log[h]);
    float s = 0.f;
    for (int i = 0; i < CSIZE; i++) { s += dt_s[i]; Acum[i] = s * Aval; }
    da_last[(size_t)(b * NHEADS + h) * NCHUNK + cc] = Acum[CSIZE - 1];
  }
  __syncthreads();
  float total = Acum[CSIZE - 1];
  w_s[tid] = dt_s[tid] * expf(total - Acum[tid]);
  float acc[4][8];
  for (int a = 0; a < 4; a++) for (int j = 0; j < 8; j++) acc[a][j] = 0.f;
  const int pi = (tid & 15) * 4, ni = (tid >> 4) * 8;
  for (int lt = 0; lt < 4; lt++) {
    __syncthreads();
    for (int i = 0; i < 4; i++) {
      int idx = tid + i * 256;
      int r = idx >> 4, c4 = (idx & 15) << 2;
      short4 v = *(const short4*)&xBCc[(row0 + lt * 64 + r) * CONVD + h * PDIM + c4];
      float wl = w_s[lt * 64 + r];
      xw[r][c4 + 0] = bf2f(v.x) * wl;
      xw[r][c4 + 1] = bf2f(v.y) * wl;
      xw[r][c4 + 2] = bf2f(v.z) * wl;
      xw[r][c4 + 3] = bf2f(v.w) * wl;
    }
    for (int i = 0; i < 8; i++) {
      int idx = tid + i * 256;
      int r = idx >> 5, c4 = (idx & 31) << 2;
      short4 v = *(const short4*)&xBCc[(row0 + lt * 64 + r) * CONVD + DINNER + c4];
      Bt[r][c4 + 0] = bf2f(v.x);
      Bt[r][c4 + 1] = bf2f(v.y);
      Bt[r][c4 + 2] = bf2f(v.z);
      Bt[r][c4 + 3] = bf2f(v.w);
    }
    __syncthreads();
    for (int l = 0; l < 64; l++) {
      float4 xv = *(const float4*)&xw[l][pi];
      float4 b0 = *(const float4*)&Bt[l][ni];
      float4 b1 = *(const float4*)&Bt[l][ni + 4];
      float xa[4] = {xv.x, xv.y, xv.z, xv.w};
      float bb[8] = {b0.x, b0.y, b0.z, b0.w, b1.x, b1.y, b1.z, b1.w};
      for (int a = 0; a < 4; a++)
        for (int j = 0; j < 8; j++)
          acc[a][j] += xa[a] * bb[j];
    }
  }
  const size_t sbase = (((size_t)b * NCHUNK + cc) * NHEADS + h) * (PDIM * NSTATE);
  for (int a = 0; a < 4; a++) {
    short o[8];
    for (int j = 0; j < 8; j++) o[j] = f2bf(acc[a][j]);
    *(s8v*)&states[sbase + (size_t)(pi + a) * NSTATE + ni] = *(const s8v*)o;
  }
}

// ----------------------------------------------- 8-step chunk scan (in-place)
// 512 blocks: (b,h) x 4 slices of the 64x128 state tile
__global__ __launch_bounds__(256) void scan_kernel(
    short* __restrict__ states, const float* __restrict__ da_last) {
  const int bh = blockIdx.x >> 2, sl = blockIdx.x & 3;
  const int b = bh >> 6, h = bh & 63;
  const int tid = threadIdx.x;
  float prev[8];
  for (int i = 0; i < 8; i++) prev[i] = 0.f;
  for (int c = 0; c < NCHUNK; c++) {
    const size_t base = (((size_t)b * NCHUNK + c) * NHEADS + h) * (PDIM * NSTATE)
                      + sl * 2048;
    const float d = expf(da_last[(size_t)bh * NCHUNK + c]);
    for (int i = 0; i < 8; i++) {
      size_t e = base + tid + i * 256;
      float s = bf2f(states[e]);
      states[e] = f2bf(prev[i]);
      prev[i] = prev[i] * d + s;
    }
  }
}

// ---------------------------------------------- SSD Y (MFMA core) -> bf16
__global__ __launch_bounds__(256) void ssd_y_kernel(
    const short* __restrict__ xBCc, const float* __restrict__ dtp,
    const float* __restrict__ A_log, const float* __restrict__ D_param,
    const short* __restrict__ prevs, short* __restrict__ y) {
  const int blk = blockIdx.x;
  const int h = blk & 63, cc = (blk >> 6) & 7, b = blk >> 9;
  const int tid = threadIdx.x;
  const int lane = tid & 63, w = tid >> 6;
  const int lr = lane & 15, q = lane >> 4;
  __shared__ float dt_s[CSIZE];
  __shared__ float Acum[CSIZE];
  __shared__ short C_s[64][136];
  __shared__ short BP_s[64][136];
  __shared__ short xdtT[64][72];
  __shared__ short Mt[64][72];
  const size_t row0 = (size_t)(b * SEQLEN + cc * CSIZE);
  dt_s[tid] = dtp[(row0 + tid) * NHEADS + h];
  __syncthreads();
  if (tid == 0) {
    float Aval = -expf(A_log[h]);
    float s = 0.f;
    for (int i = 0; i < CSIZE; i++) { s += dt_s[i]; Acum[i] = s * Aval; }
  }
  const float Dh = D_param[h];
  const size_t prevbase = (((size_t)b * NCHUNK + cc) * NHEADS + h) * (PDIM * NSTATE);
  const int wl0 = w * 16;

  for (int lt = 0; lt < 4; lt++) {
    __syncthreads();
    for (int i = 0; i < 4; i++) {
      int idx = tid + i * 256;
      int r = idx >> 4, c8 = (idx & 15) << 3;
      *(s8v*)&C_s[r][c8] =
          *(const s8v*)&xBCc[(row0 + lt * 64 + r) * CONVD + DINNER + NSTATE + c8];
      *(s8v*)&BP_s[r][c8] = *(const s8v*)&prevs[prevbase + (size_t)r * NSTATE + c8];
    }
    __syncthreads();
    // phase A: acc = C @ prev^T  (K = n = 128)
    f4v acc[4];
    for (int j = 0; j < 4; j++) for (int r = 0; r < 4; r++) acc[j][r] = 0.f;
    for (int ks = 0; ks < 4; ks++) {
      s8v a = *(const s8v*)&C_s[wl0 + lr][ks * 32 + q * 8];
      for (int j = 0; j < 4; j++) {
        s8v bb = *(const s8v*)&BP_s[j * 16 + lr][ks * 32 + q * 8];
        acc[j] = mfma_bf16(a, bb, acc[j]);
      }
    }
    for (int r = 0; r < 4; r++) {
      float e = __expf(Acum[lt * 64 + wl0 + q * 4 + r]);
      for (int j = 0; j < 4; j++) acc[j][r] *= e;
    }
    // phase B: causal s-tiles
    for (int st = 0; st <= lt; st++) {
      __syncthreads();
      for (int i = 0; i < 4; i++) {
        int idx = tid + i * 256;
        int r = idx >> 4, c8 = (idx & 15) << 3;
        *(s8v*)&BP_s[r][c8] =
            *(const s8v*)&xBCc[(row0 + st * 64 + r) * CONVD + DINNER + c8];
      }
      for (int i = 0; i < 4; i++) {
        int idx = tid + i * 256;
        int r = idx >> 4, c4 = (idx & 15) << 2;
        float dtv = dt_s[st * 64 + r];
        short4 v = *(const short4*)&xBCc[(row0 + st * 64 + r) * CONVD + h * PDIM + c4];
        xdtT[c4 + 0][r] = f2bf(bf2f(v.x) * dtv);
        xdtT[c4 + 1][r] = f2bf(bf2f(v.y) * dtv);
        xdtT[c4 + 2][r] = f2bf(bf2f(v.z) * dtv);
        xdtT[c4 + 3][r] = f2bf(bf2f(v.w) * dtv);
      }
      __syncthreads();
      f4v sacc[4];
      for (int j = 0; j < 4; j++) for (int r = 0; r < 4; r++) sacc[j][r] = 0.f;
      for (int ks = 0; ks < 4; ks++) {
        s8v a = *(const s8v*)&C_s[wl0 + lr][ks * 32 + q * 8];
        for (int j = 0; j < 4; j++) {
          s8v bb = *(const s8v*)&BP_s[j * 16 + lr][ks * 32 + q * 8];
          sacc[j] = mfma_bf16(a, bb, sacc[j]);
        }
      }
      int lbase = lt * 64 + wl0 + q * 4;
      for (int j = 0; j < 4; j++) {
        int sg = st * 64 + j * 16 + lr;
        for (int r = 0; r < 4; r++) {
          int ll = lbase + r;
          float m = (sg <= ll) ? sacc[j][r] * __expf(Acum[ll] - Acum[sg]) : 0.f;
          Mt[wl0 + q * 4 + r][j * 16 + lr] = f2bf(m);
        }
      }
      __syncthreads();
      for (int ss2 = 0; ss2 < 2; ss2++) {
        s8v a = *(const s8v*)&Mt[wl0 + lr][ss2 * 32 + q * 8];
        for (int j = 0; j < 4; j++) {
          s8v bb = *(const s8v*)&xdtT[j * 16 + lr][ss2 * 32 + q * 8];
          acc[j] = mfma_bf16(a, bb, acc[j]);
        }
      }
    }
    // epilogue: fold D*x, transpose via Mt (wave-own rows), coalesced store
    for (int j = 0; j < 4; j++)
      for (int r = 0; r < 4; r++) {
        int lrow = wl0 + q * 4 + r;
        int ll = lt * 64 + lrow;
        int p = j * 16 + lr;
        float xv = bf2f(xBCc[(row0 + ll) * CONVD + h * PDIM + p]);
        Mt[lrow][p] = f2bf(acc[j][r] + Dh * xv);
      }
    __syncthreads();
    for (int ps = 0; ps < 2; ps++) {
      int r = ps * 32 + (tid >> 3);
      int c8 = (tid & 7) * 8;
      s8v v = *(const s8v*)&Mt[r][c8];
      *(s8v*)&y[(row0 + lt * 64 + r) * DINNER + h * PDIM + c8] = v;
    }
  }
}

// -------------------------------------- gated RMSNorm -> bf16
__global__ __launch_bounds__(256) void norm_kernel(
    const short* __restrict__ y, const short* __restrict__ z,
    const float* __restrict__ norm_w, short* __restrict__ g) {
  int bl = blockIdx.x, tid = threadIdx.x;
  const short4* yrow = (const short4*)(y + (size_t)bl * DINNER);
  const short4* zrow = (const short4*)(z + (size_t)bl * DINNER);
  float gv[16];
  float ss = 0.f;
  for (int i = 0; i < 4; i++) {
    short4 yv = yrow[tid + i * 256];
    short4 zv = zrow[tid + i * 256];
    float zf[4] = {bf2f(zv.x), bf2f(zv.y), bf2f(zv.z), bf2f(zv.w)};
    float yf[4] = {bf2f(yv.x), bf2f(yv.y), bf2f(yv.z), bf2f(yv.w)};
    for (int t = 0; t < 4; t++) {
      float gg = yf[t] * (zf[t] / (1.f + expf(-zf[t])));
      gv[i * 4 + t] = gg;
      ss += gg * gg;
    }
  }
  for (int off = 32; off > 0; off >>= 1) ss += __shfl_down(ss, off);
  __shared__ float red[4];
  __shared__ float rsS;
  if ((tid & 63) == 0) red[tid >> 6] = ss;
  __syncthreads();
  if (tid == 0) rsS = rsqrtf((red[0] + red[1] + red[2] + red[3]) * (1.f / 4096.f) + 1e-5f);
  __syncthreads();
  float rs = rsS;
  for (int i = 0; i < 4; i++) {
    int j4 = (tid + i * 256) * 4;
    float4 nw = *(const float4*)&norm_w[j4];
    short4 o;
    o.x = f2bf(gv[i * 4 + 0] * rs * nw.x);
    o.y = f2bf(gv[i * 4 + 1] * rs * nw.y);
    o.z = f2bf(gv[i * 4 + 2] * rs * nw.z);
    o.w = f2bf(gv[i * 4 + 3] * rs * nw.w);
    *(short4*)&g[(size_t)bl * DINNER + j4] = o;
  }
}

extern "C" void kernel_launch(void* const* d_in, const int* in_sizes, int n_in,
                              void* d_out, int out_size, void* d_ws, size_t ws_size,
                              hipStream_t stream) {
  const float* hidden  = (const float*)d_in[0];
  const float* W_in    = (const float*)d_in[1];
  const float* conv_w  = (const float*)d_in[2];
  const float* conv_b  = (const float*)d_in[3];
  const float* dt_bias = (const float*)d_in[4];
  const float* A_log   = (const float*)d_in[5];
  const float* D_param = (const float*)d_in[6];
  const float* norm_w  = (const float*)d_in[7];
  const float* W_out   = (const float*)d_in[8];
  float* out = (float*)d_out;

  // ---- workspace arena (122,687,488 bytes), phase-overlapped regions ----
  char* ws = (char*)d_ws;
  short* z_bf  = (short*)(ws + 0);                     // 33,554,432
  float* dtb   = (float*)(ws + 33554432);              //  1,048,576
  float* da_l  = (float*)(ws + 34603008);              //  4 KB
  short* xbc_pre = (short*)(ws + 34607104);            // 35,651,584 (GEMM1->conv)
  short* y_bf    = (short*)(ws + 34607104);            // 33,554,432 (ssd_y->norm)
  short* hid_bf  = (short*)(ws + 70258688);            // 16,777,216 (casts->GEMM1)
  short* win_bf  = (short*)(ws + 87035904);            // 34,865,152 (casts->GEMM1)
  short* xBCc    = (short*)(ws + 70258688);            // 35,651,584 (conv->ssd)
  short* states  = (short*)(ws + 105910272);           // 16,777,216 (ssd)
  short* g_bf    = (short*)(ws + 70258688);            // 33,554,432 (norm->GEMM2)
  short* wout_bf = (short*)(ws + 105910272);           // 16,777,216 (cast->GEMM2)
  if (ws_size < (size_t)122687488) return;

  cast_bf16_kernel<<<8192, 256, 0, stream>>>(hidden, hid_bf, 2097152);
  cast_bf16_kernel<<<17024, 256, 0, stream>>>(W_in, win_bf, 4358144);

  gemm1_kernel<<<2144, 256, 0, stream>>>(hid_bf, win_bf, z_bf, xbc_pre, dtb);

  conv_silu_kernel<<<dim3(17, 4096), 256, 0, stream>>>(xbc_pre, conv_w, conv_b, xBCc);
  dt_kernel<<<1024, 256, 0, stream>>>(dtb, dt_bias);

  ssd_states_kernel<<<1024, 256, 0, stream>>>(xBCc, dtb, A_log, states, da_l);
  scan_kernel<<<512, 256, 0, stream>>>(states, da_l);
  ssd_y_kernel<<<1024, 256, 0, stream>>>(xBCc, dtb, A_log, D_param, states, y_bf);

  norm_kernel<<<4096, 256, 0, stream>>>(y_bf, z_bf, norm_w, g_bf);
  cast_bf16_kernel<<<8192, 256, 0, stream>>>(W_out, wout_bf, 2097152);

  gemm_nt_bf16<<<512, 256, 0, stream>>>(g_bf, wout_bf, out, 4096, 2048, 4096);
}